// Round 5
// baseline (129.090 us; speedup 1.0000x reference)
//
#include <hip/hip_runtime.h>
#include <hip/hip_bf16.h>
#include <stdint.h>

// Problem constants (fixed by reference)
#define NB    8
#define NS    2048
#define NE    1024
#define NH    16
#define NDK   64
#define MTOK  (NB*NS)      // 16384 tokens

typedef __attribute__((ext_vector_type(8))) short bf16x8;
typedef __attribute__((ext_vector_type(4))) float f32x4;

// round-to-nearest-even f32 -> bf16 bits
__device__ __forceinline__ ushort f2bf(float f) {
  uint32_t u = __float_as_uint(f);
  u += 0x7FFFu + ((u >> 16) & 1u);
  return (ushort)(u >> 16);
}

__device__ __forceinline__ void gload16(const void* g, void* l) {
  __builtin_amdgcn_global_load_lds(
      (const __attribute__((address_space(1))) void*)g,
      (__attribute__((address_space(3))) void*)l, 16, 0, 0);
}

// ---------------- f32 -> bf16 cast (vectorized) ----------------
__global__ __launch_bounds__(256) void cvt_bf16(const float* __restrict__ in,
                                                ushort* __restrict__ out, int n4) {
  int stride = gridDim.x * blockDim.x;
  for (int j = blockIdx.x * blockDim.x + threadIdx.x; j < n4; j += stride) {
    float4 v = ((const float4*)in)[j];
    ushort4 o;
    o.x = f2bf(v.x); o.y = f2bf(v.y); o.z = f2bf(v.z); o.w = f2bf(v.w);
    ((ushort4*)out)[j] = o;
  }
}

// ---------------- bf16 GEMM: C[m,n] = sum_k A[m,k]*B[n,k] ----------------
// 128x128 tile, BK=32, 4 waves (2x2), 4x4 16x16x32 fragments per wave.
// XCD-chunked block swizzle (T1) + LDS slot XOR-swizzle (T2): LDS content at
// (row, slot) holds global (row, slot ^ (row&3)); inverse applied on the
// global source of global_load_lds (linear LDS dest), XOR applied on ds_read.
#define BM 128
#define BN 128
#define BK 32

__device__ __forceinline__ void swz_block(int& br, int& bc) {
  int b  = blockIdx.x;                    // nwg = 1024, 8 XCDs, cpx = 128
  int wg = ((b & 7) << 7) | (b >> 3);     // (b%8)*128 + b/8  (bijective)
  br = wg >> 3;                           // 0..127
  bc = wg & 7;                            // 0..7
}

// f32-output variant (GEMM2)
__global__ __launch_bounds__(256) void gemm_bt(const ushort* __restrict__ A,
                                               const ushort* __restrict__ Bm,
                                               float* __restrict__ C,
                                               int M, int N, int K) {
  __shared__ ushort As[2][BM * BK];
  __shared__ ushort Bs[2][BN * BK];

  int tid  = threadIdx.x;
  int lane = tid & 63;
  int w    = tid >> 6;
  int wr   = w >> 1, wc = w & 1;
  int br, bc;
  swz_block(br, bc);

  const ushort* Abase = A  + (size_t)(br * BM) * K;
  const ushort* Bbase = Bm + (size_t)(bc * BN) * K;

  int srow = lane >> 2;                          // 0..15 rows within a 1KB chunk
  int skk  = (((lane & 3) ^ (srow & 3)) * 8);    // inverse-swizzled k-slot

  f32x4 zero = {0.f, 0.f, 0.f, 0.f};
  f32x4 acc[4][4];
#pragma unroll
  for (int m = 0; m < 4; ++m)
#pragma unroll
    for (int n = 0; n < 4; ++n) acc[m][n] = zero;

  int NKT = K / BK;
  int cur = 0;

#pragma unroll
  for (int j = 0; j < 2; ++j) {
    int c = w * 2 + j;
    gload16(Abase + (size_t)(c * 16 + srow) * K + skk, &As[0][c * 512]);
    gload16(Bbase + (size_t)(c * 16 + srow) * K + skk, &Bs[0][c * 512]);
  }

  int fr = lane & 15;
  int ks = lane >> 4;                  // k-slot 0..3
  int fro = (ks ^ (fr & 3)) * 8;       // swizzled k-offset for ds_read

  for (int kt = 0; kt < NKT; ++kt) {
    __syncthreads();
    if (kt + 1 < NKT) {
      int k0 = (kt + 1) * BK;
#pragma unroll
      for (int j = 0; j < 2; ++j) {
        int c = w * 2 + j;
        gload16(Abase + (size_t)(c * 16 + srow) * K + k0 + skk, &As[cur ^ 1][c * 512]);
        gload16(Bbase + (size_t)(c * 16 + srow) * K + k0 + skk, &Bs[cur ^ 1][c * 512]);
      }
    }
    bf16x8 af[4], bfr[4];
#pragma unroll
    for (int m = 0; m < 4; ++m)
      af[m] = *(const bf16x8*)&As[cur][(wr * 64 + m * 16 + fr) * BK + fro];
#pragma unroll
    for (int n = 0; n < 4; ++n)
      bfr[n] = *(const bf16x8*)&Bs[cur][(wc * 64 + n * 16 + fr) * BK + fro];
#pragma unroll
    for (int m = 0; m < 4; ++m)
#pragma unroll
      for (int n = 0; n < 4; ++n)
        acc[m][n] = __builtin_amdgcn_mfma_f32_16x16x32_bf16(af[m], bfr[n], acc[m][n], 0, 0, 0);
    cur ^= 1;
  }

  int row0 = br * BM + wr * 64 + (lane >> 4) * 4;
  int col0 = bc * BN + wc * 64 + (lane & 15);
#pragma unroll
  for (int m = 0; m < 4; ++m)
#pragma unroll
    for (int n = 0; n < 4; ++n)
#pragma unroll
      for (int i = 0; i < 4; ++i)
        C[(size_t)(row0 + m * 16 + i) * N + col0 + n * 16] = acc[m][n][i];
}

// bf16-output variant with fused quantum projection epilogue (GEMM1):
// qq[m,n] = cos(theta[n&63]) * cos(proj[m,n]), stored bf16.
__global__ __launch_bounds__(256) void gemm_bt_cos(const ushort* __restrict__ A,
                                                   const ushort* __restrict__ Bm,
                                                   ushort* __restrict__ Cq,
                                                   const float* __restrict__ theta,
                                                   int M, int N, int K) {
  __shared__ ushort As[2][BM * BK];
  __shared__ ushort Bs[2][BN * BK];

  int tid  = threadIdx.x;
  int lane = tid & 63;
  int w    = tid >> 6;
  int wr   = w >> 1, wc = w & 1;
  int br, bc;
  swz_block(br, bc);

  const ushort* Abase = A  + (size_t)(br * BM) * K;
  const ushort* Bbase = Bm + (size_t)(bc * BN) * K;

  int srow = lane >> 2;
  int skk  = (((lane & 3) ^ (srow & 3)) * 8);

  f32x4 zero = {0.f, 0.f, 0.f, 0.f};
  f32x4 acc[4][4];
#pragma unroll
  for (int m = 0; m < 4; ++m)
#pragma unroll
    for (int n = 0; n < 4; ++n) acc[m][n] = zero;

  int NKT = K / BK;
  int cur = 0;

#pragma unroll
  for (int j = 0; j < 2; ++j) {
    int c = w * 2 + j;
    gload16(Abase + (size_t)(c * 16 + srow) * K + skk, &As[0][c * 512]);
    gload16(Bbase + (size_t)(c * 16 + srow) * K + skk, &Bs[0][c * 512]);
  }

  int fr = lane & 15;
  int ks = lane >> 4;
  int fro = (ks ^ (fr & 3)) * 8;

  for (int kt = 0; kt < NKT; ++kt) {
    __syncthreads();
    if (kt + 1 < NKT) {
      int k0 = (kt + 1) * BK;
#pragma unroll
      for (int j = 0; j < 2; ++j) {
        int c = w * 2 + j;
        gload16(Abase + (size_t)(c * 16 + srow) * K + k0 + skk, &As[cur ^ 1][c * 512]);
        gload16(Bbase + (size_t)(c * 16 + srow) * K + k0 + skk, &Bs[cur ^ 1][c * 512]);
      }
    }
    bf16x8 af[4], bfr[4];
#pragma unroll
    for (int m = 0; m < 4; ++m)
      af[m] = *(const bf16x8*)&As[cur][(wr * 64 + m * 16 + fr) * BK + fro];
#pragma unroll
    for (int n = 0; n < 4; ++n)
      bfr[n] = *(const bf16x8*)&Bs[cur][(wc * 64 + n * 16 + fr) * BK + fro];
#pragma unroll
    for (int m = 0; m < 4; ++m)
#pragma unroll
      for (int n = 0; n < 4; ++n)
        acc[m][n] = __builtin_amdgcn_mfma_f32_16x16x32_bf16(af[m], bfr[n], acc[m][n], 0, 0, 0);
    cur ^= 1;
  }

  // theta index for col = bc*128 + wc*64 + n*16 + fr is (n*16+fr) & 63 = n*16+fr
  float ct[4];
#pragma unroll
  for (int n = 0; n < 4; ++n) ct[n] = __cosf(theta[n * 16 + fr]);

  int row0 = br * BM + wr * 64 + (lane >> 4) * 4;
  int col0 = bc * BN + wc * 64 + fr;
#pragma unroll
  for (int m = 0; m < 4; ++m)
#pragma unroll
    for (int n = 0; n < 4; ++n)
#pragma unroll
      for (int i = 0; i < 4; ++i)
        Cq[(size_t)(row0 + m * 16 + i) * N + col0 + n * 16] =
            f2bf(ct[n] * __cosf(acc[m][n][i]));
}

// ---------------- per-token head-vs-head attention via MFMA ----------------
// 1 wave = 1 token. Scores: S = H^T H via self-product MFMA; softmax per
// column; PV A-frag = shuffled P (K padded to 32), B-frag = LDS-transposed H.
__global__ __launch_bounds__(256) void attn_quantum(const ushort* __restrict__ qqb,
                                                    ushort* __restrict__ aout) {
  __shared__ ushort T[4][64 * 32];
  int tid = threadIdx.x;
  int wv  = tid >> 6, l = tid & 63;
  size_t tok = (size_t)blockIdx.x * 4 + wv;
  const ushort* src = qqb + tok * NE;
  ushort* Tw = T[wv];

  int h  = l & 15;   // head / fragment row-col index
  int kb = l >> 4;   // k-block 0..3

  bf16x8 f0 = *(const bf16x8*)(src + h * 64 + kb * 8);
  bf16x8 f1 = *(const bf16x8*)(src + h * 64 + kb * 8 + 32);

  // transpose into LDS (swizzled): T[d][h] = H[d][h]
#pragma unroll
  for (int jj = 0; jj < 8; ++jj) {
    int d0 = kb * 8 + jj;
    int d1 = d0 + 32;
    Tw[d0 * 32 + (((h >> 3) ^ ((d0 >> 3) & 3)) << 3) + (h & 7)] = (ushort)f0[jj];
    Tw[d1 * 32 + (((h >> 3) ^ ((d1 >> 3) & 3)) << 3) + (h & 7)] = (ushort)f1[jj];
  }

  // scores: S[i][j] = sum_d qq[i*64+d]*qq[j*64+d]; frag is both A and B
  f32x4 sa = {0.f, 0.f, 0.f, 0.f};
  sa = __builtin_amdgcn_mfma_f32_16x16x32_bf16(f0, f0, sa, 0, 0, 0);
  sa = __builtin_amdgcn_mfma_f32_16x16x32_bf16(f1, f1, sa, 0, 0, 0);

  float s[4];
#pragma unroll
  for (int i = 0; i < 4; ++i) s[i] = sa[i] * 0.125f;   // 1/sqrt(64)

  float mx = fmaxf(fmaxf(s[0], s[1]), fmaxf(s[2], s[3]));
  mx = fmaxf(mx, __shfl_xor(mx, 16));
  mx = fmaxf(mx, __shfl_xor(mx, 32));
  float e[4], sum = 0.f;
#pragma unroll
  for (int i = 0; i < 4; ++i) { e[i] = __expf(s[i] - mx); sum += e[i]; }
  sum += __shfl_xor(sum, 16);
  sum += __shfl_xor(sum, 32);
  float inv = 1.f / sum;
#pragma unroll
  for (int i = 0; i < 4; ++i) e[i] *= inv;   // P[g][h], normalized

  // regroup P into PV A-frag: lane (h,kb) needs P[kb*8+jj][h], jj=0..7
  int s1 = h + (kb & 1) * 32;
  float q1[4], q2[4];
#pragma unroll
  for (int i = 0; i < 4; ++i) {
    q1[i] = __shfl(e[i], s1);
    q2[i] = __shfl(e[i], s1 + 16);
  }
  bool live = (kb < 2);
  bf16x8 pa;
#pragma unroll
  for (int i = 0; i < 4; ++i) {
    pa[i]     = live ? (short)f2bf(q1[i]) : (short)0;
    pa[4 + i] = live ? (short)f2bf(q2[i]) : (short)0;
  }

  __syncthreads();  // LDS transpose visible

  f32x4 o[4];
#pragma unroll
  for (int c = 0; c < 4; ++c) {
    int r = c * 16 + h;
    int slot = (kb & 1) ^ ((r >> 3) & 3);
    bf16x8 bfrag = *(const bf16x8*)&Tw[r * 32 + slot * 8];
    f32x4 z = {0.f, 0.f, 0.f, 0.f};
    o[c] = __builtin_amdgcn_mfma_f32_16x16x32_bf16(pa, bfrag, z, 0, 0, 0);
  }

  ushort* dst = aout + tok * NE;
#pragma unroll
  for (int c = 0; c < 4; ++c)
#pragma unroll
    for (int i = 0; i < 4; ++i)
      dst[(kb * 4 + i) * NDK + c * 16 + h] = f2bf(o[c][i]);
}

// ---------------- launch ----------------
extern "C" void kernel_launch(void* const* d_in, const int* in_sizes, int n_in,
                              void* d_out, int out_size, void* d_ws, size_t ws_size,
                              hipStream_t stream) {
  const float* x     = (const float*)d_in[0];
  const float* W     = (const float*)d_in[1];
  const float* theta = (const float*)d_in[2];
  float* out = (float*)d_out;

  char* ws = (char*)d_ws;
  ushort* xb  = (ushort*)ws;                                   // 32 MB
  ushort* Wb  = (ushort*)(ws + (size_t)MTOK * NE * 2);         // 2 MB
  ushort* qqb = (ushort*)(ws + (size_t)MTOK * NE * 2 + (size_t)NE * NE * 2); // 32 MB
  ushort* aout = xb;  // reuse: xb dead after GEMM1

  cvt_bf16<<<1024, 256, 0, stream>>>(x, xb, MTOK * NE / 4);
  cvt_bf16<<<256, 256, 0, stream>>>(W, Wb, NE * NE / 4);

  int nwg = (NE / BN) * (MTOK / BM);  // 8 * 128 = 1024, divisible by 8
  gemm_bt_cos<<<nwg, 256, 0, stream>>>(xb, Wb, qqb, theta, MTOK, NE, NE);

  attn_quantum<<<MTOK / 4, 256, 0, stream>>>(qqb, aout);

  gemm_bt<<<nwg, 256, 0, stream>>>(aout, Wb, out, MTOK, NE, NE);
}

// Round 6
// 109.567 us; speedup vs baseline: 1.1782x; 1.1782x over previous
//
#include <hip/hip_runtime.h>
#include <hip/hip_bf16.h>
#include <stdint.h>

// Problem constants (fixed by reference)
#define NB    8
#define NS    2048
#define NE    1024
#define NH    16
#define NDK   64
#define MTOK  (NB*NS)      // 16384 tokens

typedef __attribute__((ext_vector_type(8))) short bf16x8;
typedef __attribute__((ext_vector_type(4))) float f32x4;

// round-to-nearest-even f32 -> bf16 bits
__device__ __forceinline__ ushort f2bf(float f) {
  uint32_t u = __float_as_uint(f);
  u += 0x7FFFu + ((u >> 16) & 1u);
  return (ushort)(u >> 16);
}

__device__ __forceinline__ void gload16(const void* g, void* l) {
  __builtin_amdgcn_global_load_lds(
      (const __attribute__((address_space(1))) void*)g,
      (__attribute__((address_space(3))) void*)l, 16, 0, 0);
}

// ---------------- f32 -> bf16 cast (vectorized) ----------------
__global__ __launch_bounds__(256) void cvt_bf16(const float* __restrict__ in,
                                                ushort* __restrict__ out, int n4) {
  int stride = gridDim.x * blockDim.x;
  for (int j = blockIdx.x * blockDim.x + threadIdx.x; j < n4; j += stride) {
    float4 v = ((const float4*)in)[j];
    ushort4 o;
    o.x = f2bf(v.x); o.y = f2bf(v.y); o.z = f2bf(v.z); o.w = f2bf(v.w);
    ((ushort4*)out)[j] = o;
  }
}

// ---------------- 256x256 8-phase bf16 GEMM (C = A * B^T) ----------------
// 512 threads = 8 waves (2 Mrows x 4 Ncols); BK=64; 16 K-tiles at K=1024.
// LDS 128 KB: As/Bs double-buffered 256x64 bf16 tiles, 128 B rows, 8 chunks
// of 16 B per row, XOR swizzle slot = chunk ^ (row&7) (inverse pre-applied to
// the per-lane GLOBAL source; LDS dest of global_load_lds stays linear).
// Phase q (q=0..3 per K-tile): kk = q>>1, mi-quad = q&1; 16 MFMA per phase.
// Staging: tile t stages tile t+1 into buf^1: B-Mh0@q0, B-Mh1@q1, A-Mh0@q2,
// A-Mh1@q3 (B needed first at t+1 q0; A-Mh1 needed last at t+1 q1/q3).
// Guards: vmcnt(2) before end-barrier of q0 (protects A-Mh1(t), staged
// (t-1,q3)) and of q3 (protects all t+1 halves staged through q2). Final tile
// uses vmcnt(0) at q0. Never drains to 0 otherwise (T4).
#define GM 256
#define GN 256
#define GK 64

template<int EPI>   // 0: f32 C out; 1: cos(theta)*cos(acc) -> bf16 out
__global__ __launch_bounds__(512, 2) void gemm256(const ushort* __restrict__ A,
                                                  const ushort* __restrict__ Bm,
                                                  float* __restrict__ Cf,
                                                  ushort* __restrict__ Cq,
                                                  const float* __restrict__ theta,
                                                  int M, int N, int K) {
  __shared__ ushort As[2][GM * GK];   // 32 KB per buffer
  __shared__ ushort Bs[2][GN * GK];

  const int tid  = threadIdx.x;
  const int wid  = tid >> 6;
  const int lane = tid & 63;
  const int wr   = wid >> 2;        // 0..1
  const int wc   = wid & 3;         // 0..3
  const int fr   = lane & 15;
  const int ks   = lane >> 4;       // 0..3

  // XCD-chunked bijective swizzle: 256 blocks, 32 per XCD (A-panel locality)
  int b  = blockIdx.x;
  int wg = ((b & 7) << 5) | (b >> 3);
  int br = wg >> 2, bc = wg & 3;

  const ushort* Abase = A  + (size_t)(br * GM) * K;
  const ushort* Bbase = Bm + (size_t)(bc * GN) * K;

  // stage constants: lane covers (row base + lane>>3, slot lane&7);
  // source chunk = slot ^ (row&7)  (row&7 == lane>>3 for our 8-row stripes)
  const int srow = lane >> 3;
  const int sch8 = ((lane & 7) ^ srow) * 8;   // ushort offset of src chunk

  // ds_read slot offsets (ushorts): chunk = kk*4 + ks, slot = chunk ^ (row&7),
  // and row&7 == fr&7 for all fragment rows.
  const int sA0 = ((0 + ks) ^ (fr & 7)) * 8;  // kk = 0
  const int sA1 = ((4 + ks) ^ (fr & 7)) * 8;  // kk = 1

  f32x4 zero = {0.f, 0.f, 0.f, 0.f};
  f32x4 acc[8][4];
#pragma unroll
  for (int mi = 0; mi < 8; ++mi)
#pragma unroll
    for (int ni = 0; ni < 4; ++ni) acc[mi][ni] = zero;

  auto stA = [&](int buf, int mh, int kt) {
#pragma unroll
    for (int j = 0; j < 2; ++j) {
      int rl = mh * 128 + j * 64 + wid * 8;       // wave-uniform LDS row base
      gload16(Abase + (size_t)(rl + srow) * K + kt * GK + sch8,
              &As[buf][rl * GK]);
    }
  };
  auto stB = [&](int buf, int mh, int kt) {
#pragma unroll
    for (int j = 0; j < 2; ++j) {
      int rl = mh * 128 + j * 64 + wid * 8;
      gload16(Bbase + (size_t)(rl + srow) * K + kt * GK + sch8,
              &Bs[buf][rl * GK]);
    }
  };

  // prologue: stage tile 0 fully into buf 0, drain, enter loop
  stB(0, 0, 0); stB(0, 1, 0); stA(0, 0, 0); stA(0, 1, 0);
  asm volatile("s_waitcnt vmcnt(0)" ::: "memory");
  __builtin_amdgcn_s_barrier();

  const int NKT = K / GK;   // 16
  int cur = 0;
  for (int t = 0; t < NKT; ++t) {
    const ushort* Ac = As[cur];
    const ushort* Bc = Bs[cur];
    const int nb = cur ^ 1;
    const bool pf = (t + 1 < NKT);
    bf16x8 af[4], bv[4];

    // ---- phase q0: kk=0, mi 0-3 ---- stage B-Mh0(t+1)
#pragma unroll
    for (int mi = 0; mi < 4; ++mi)
      af[mi] = *(const bf16x8*)&Ac[(mi * 32 + wr * 16 + fr) * GK + sA0];
#pragma unroll
    for (int ni = 0; ni < 4; ++ni)
      bv[ni] = *(const bf16x8*)&Bc[(ni * 64 + wc * 16 + fr) * GK + sA0];
    if (pf) stB(nb, 0, t + 1);
    __builtin_amdgcn_sched_barrier(0);
    __builtin_amdgcn_s_setprio(1);
#pragma unroll
    for (int mi = 0; mi < 4; ++mi)
#pragma unroll
      for (int ni = 0; ni < 4; ++ni)
        acc[mi][ni] = __builtin_amdgcn_mfma_f32_16x16x32_bf16(af[mi], bv[ni], acc[mi][ni], 0, 0, 0);
    __builtin_amdgcn_s_setprio(0);
    __builtin_amdgcn_sched_barrier(0);
    if (pf) asm volatile("s_waitcnt vmcnt(2)" ::: "memory");   // A-Mh1(t) landed
    else    asm volatile("s_waitcnt vmcnt(0)" ::: "memory");   // tail drain
    __builtin_amdgcn_s_barrier();

    // ---- phase q1: kk=0, mi 4-7 ---- stage B-Mh1(t+1)
#pragma unroll
    for (int mi = 0; mi < 4; ++mi)
      af[mi] = *(const bf16x8*)&Ac[((mi + 4) * 32 + wr * 16 + fr) * GK + sA0];
    if (pf) stB(nb, 1, t + 1);
    __builtin_amdgcn_sched_barrier(0);
    __builtin_amdgcn_s_setprio(1);
#pragma unroll
    for (int mi = 0; mi < 4; ++mi)
#pragma unroll
      for (int ni = 0; ni < 4; ++ni)
        acc[mi + 4][ni] = __builtin_amdgcn_mfma_f32_16x16x32_bf16(af[mi], bv[ni], acc[mi + 4][ni], 0, 0, 0);
    __builtin_amdgcn_s_setprio(0);
    __builtin_amdgcn_sched_barrier(0);
    __builtin_amdgcn_s_barrier();

    // ---- phase q2: kk=1, mi 0-3 ---- stage A-Mh0(t+1)
#pragma unroll
    for (int mi = 0; mi < 4; ++mi)
      af[mi] = *(const bf16x8*)&Ac[(mi * 32 + wr * 16 + fr) * GK + sA1];
#pragma unroll
    for (int ni = 0; ni < 4; ++ni)
      bv[ni] = *(const bf16x8*)&Bc[(ni * 64 + wc * 16 + fr) * GK + sA1];
    if (pf) stA(nb, 0, t + 1);
    __builtin_amdgcn_sched_barrier(0);
    __builtin_amdgcn_s_setprio(1);
#pragma unroll
    for (int mi = 0; mi < 4; ++mi)
#pragma unroll
      for (int ni = 0; ni < 4; ++ni)
        acc[mi][ni] = __builtin_amdgcn_mfma_f32_16x16x32_bf16(af[mi], bv[ni], acc[mi][ni], 0, 0, 0);
    __builtin_amdgcn_s_setprio(0);
    __builtin_amdgcn_sched_barrier(0);
    __builtin_amdgcn_s_barrier();

    // ---- phase q3: kk=1, mi 4-7 ---- stage A-Mh1(t+1)
#pragma unroll
    for (int mi = 0; mi < 4; ++mi)
      af[mi] = *(const bf16x8*)&Ac[((mi + 4) * 32 + wr * 16 + fr) * GK + sA1];
    if (pf) stA(nb, 1, t + 1);
    __builtin_amdgcn_sched_barrier(0);
    __builtin_amdgcn_s_setprio(1);
#pragma unroll
    for (int mi = 0; mi < 4; ++mi)
#pragma unroll
      for (int ni = 0; ni < 4; ++ni)
        acc[mi + 4][ni] = __builtin_amdgcn_mfma_f32_16x16x32_bf16(af[mi], bv[ni], acc[mi + 4][ni], 0, 0, 0);
    __builtin_amdgcn_s_setprio(0);
    __builtin_amdgcn_sched_barrier(0);
    if (pf) asm volatile("s_waitcnt vmcnt(2)" ::: "memory");   // t+1 halves thru q2 landed
    __builtin_amdgcn_s_barrier();

    cur ^= 1;
  }

  // ---- epilogue ----
  const int colL = wc * 16 + fr;          // col mod 64 == colL (< 64)
  float ct = 0.f;
  if (EPI == 1) ct = __cosf(theta[colL]);
#pragma unroll
  for (int mi = 0; mi < 8; ++mi) {
    int row0 = br * GM + mi * 32 + wr * 16 + ks * 4;
#pragma unroll
    for (int ni = 0; ni < 4; ++ni) {
      size_t cbase = (size_t)row0 * N + bc * GN + ni * 64 + colL;
#pragma unroll
      for (int i = 0; i < 4; ++i) {
        if (EPI == 1)
          Cq[cbase + (size_t)i * N] = f2bf(ct * __cosf(acc[mi][ni][i]));
        else
          Cf[cbase + (size_t)i * N] = acc[mi][ni][i];
      }
    }
  }
}

// ---------------- per-token head-vs-head attention via MFMA ----------------
// 1 wave = 1 token. Scores: S = H^T H via self-product MFMA; softmax per
// column; PV A-frag = shuffled P (K padded to 32), B-frag = LDS-transposed H.
__global__ __launch_bounds__(256) void attn_quantum(const ushort* __restrict__ qqb,
                                                    ushort* __restrict__ aout) {
  __shared__ ushort T[4][64 * 32];
  int tid = threadIdx.x;
  int wv  = tid >> 6, l = tid & 63;
  size_t tok = (size_t)blockIdx.x * 4 + wv;
  const ushort* src = qqb + tok * NE;
  ushort* Tw = T[wv];

  int h  = l & 15;   // head / fragment row-col index
  int kb = l >> 4;   // k-block 0..3

  bf16x8 f0 = *(const bf16x8*)(src + h * 64 + kb * 8);
  bf16x8 f1 = *(const bf16x8*)(src + h * 64 + kb * 8 + 32);

  // transpose into LDS (swizzled): T[d][h] = H[d][h]
#pragma unroll
  for (int jj = 0; jj < 8; ++jj) {
    int d0 = kb * 8 + jj;
    int d1 = d0 + 32;
    Tw[d0 * 32 + (((h >> 3) ^ ((d0 >> 3) & 3)) << 3) + (h & 7)] = (ushort)f0[jj];
    Tw[d1 * 32 + (((h >> 3) ^ ((d1 >> 3) & 3)) << 3) + (h & 7)] = (ushort)f1[jj];
  }

  // scores: S[i][j] = sum_d qq[i*64+d]*qq[j*64+d]; frag is both A and B
  f32x4 sa = {0.f, 0.f, 0.f, 0.f};
  sa = __builtin_amdgcn_mfma_f32_16x16x32_bf16(f0, f0, sa, 0, 0, 0);
  sa = __builtin_amdgcn_mfma_f32_16x16x32_bf16(f1, f1, sa, 0, 0, 0);

  float s[4];
#pragma unroll
  for (int i = 0; i < 4; ++i) s[i] = sa[i] * 0.125f;   // 1/sqrt(64)

  float mx = fmaxf(fmaxf(s[0], s[1]), fmaxf(s[2], s[3]));
  mx = fmaxf(mx, __shfl_xor(mx, 16));
  mx = fmaxf(mx, __shfl_xor(mx, 32));
  float e[4], sum = 0.f;
#pragma unroll
  for (int i = 0; i < 4; ++i) { e[i] = __expf(s[i] - mx); sum += e[i]; }
  sum += __shfl_xor(sum, 16);
  sum += __shfl_xor(sum, 32);
  float inv = 1.f / sum;
#pragma unroll
  for (int i = 0; i < 4; ++i) e[i] *= inv;   // P[g][h], normalized

  // regroup P into PV A-frag: lane (h,kb) needs P[kb*8+jj][h], jj=0..7
  int s1 = h + (kb & 1) * 32;
  float q1[4], q2[4];
#pragma unroll
  for (int i = 0; i < 4; ++i) {
    q1[i] = __shfl(e[i], s1);
    q2[i] = __shfl(e[i], s1 + 16);
  }
  bool live = (kb < 2);
  bf16x8 pa;
#pragma unroll
  for (int i = 0; i < 4; ++i) {
    pa[i]     = live ? (short)f2bf(q1[i]) : (short)0;
    pa[4 + i] = live ? (short)f2bf(q2[i]) : (short)0;
  }

  __syncthreads();  // LDS transpose visible

  f32x4 o[4];
#pragma unroll
  for (int c = 0; c < 4; ++c) {
    int r = c * 16 + h;
    int slot = (kb & 1) ^ ((r >> 3) & 3);
    bf16x8 bfrag = *(const bf16x8*)&Tw[r * 32 + slot * 8];
    f32x4 z = {0.f, 0.f, 0.f, 0.f};
    o[c] = __builtin_amdgcn_mfma_f32_16x16x32_bf16(pa, bfrag, z, 0, 0, 0);
  }

  ushort* dst = aout + tok * NE;
#pragma unroll
  for (int c = 0; c < 4; ++c)
#pragma unroll
    for (int i = 0; i < 4; ++i)
      dst[(kb * 4 + i) * NDK + c * 16 + h] = f2bf(o[c][i]);
}

// ---------------- launch ----------------
extern "C" void kernel_launch(void* const* d_in, const int* in_sizes, int n_in,
                              void* d_out, int out_size, void* d_ws, size_t ws_size,
                              hipStream_t stream) {
  const float* x     = (const float*)d_in[0];
  const float* W     = (const float*)d_in[1];
  const float* theta = (const float*)d_in[2];
  float* out = (float*)d_out;

  char* ws = (char*)d_ws;
  ushort* xb  = (ushort*)ws;                                   // 32 MB
  ushort* Wb  = (ushort*)(ws + (size_t)MTOK * NE * 2);         // 2 MB
  ushort* qqb = (ushort*)(ws + (size_t)MTOK * NE * 2 + (size_t)NE * NE * 2); // 32 MB
  ushort* aout = xb;  // reuse: xb dead after GEMM1

  cvt_bf16<<<1024, 256, 0, stream>>>(x, xb, MTOK * NE / 4);
  cvt_bf16<<<256, 256, 0, stream>>>(W, Wb, NE * NE / 4);

  int nwg = (MTOK / GM) * (NE / GN);  // 64 * 4 = 256 blocks, 1 per CU
  gemm256<1><<<nwg, 512, 0, stream>>>(xb, Wb, nullptr, qqb, theta, MTOK, NE, NE);

  attn_quantum<<<MTOK / 4, 256, 0, stream>>>(qqb, aout);

  gemm256<0><<<nwg, 512, 0, stream>>>(aout, Wb, out, nullptr, nullptr, MTOK, NE, NE);
}